// Round 1
// baseline (488.019 us; speedup 1.0000x reference)
//
#include <hip/hip_runtime.h>
#include <stdint.h>

typedef __attribute__((ext_vector_type(8))) short bf16x8;
typedef __attribute__((ext_vector_type(4))) float f32x4;

__device__ __forceinline__ unsigned short f2bf(float f) {
    union { float f; uint32_t u; } v; v.f = f;
    uint32_t r = (v.u + 0x7FFFu + ((v.u >> 16) & 1u)) >> 16;
    return (unsigned short)r;
}
__device__ __forceinline__ float bf2f(unsigned short u) {
    union { uint32_t u; float f; } v; v.u = ((uint32_t)u) << 16; return v.f;
}

#define WP_ELEMS  1081344      // 64 ktiles * 528 rows * 32 k
#define W2P_ELEMS 2211840      // 144 rows * 15360 k
#define B_OFF     42240        // LDS byte offset of B staging (A is 528*80=42240)

// ---- pack conv weights (+shape/cam rows 512..524) to bf16, K-tiled [kt][row][k] ----
__global__ void pack_convw_kernel(const float* __restrict__ cw,
                                  const float* __restrict__ sw,
                                  const float* __restrict__ camw,
                                  unsigned short* __restrict__ Wp) {
    int gid = blockIdx.x * 256 + threadIdx.x;
    if (gid >= WP_ELEMS) return;
    int kt  = gid / 16896;
    int rem = gid - kt * 16896;
    int row = rem >> 5;
    int c   = rem & 31;
    int k   = kt * 32 + c;
    float v = 0.f;
    if (row < 512)      v = cw[row * 2048 + k];
    else if (row < 522) v = sw[(row - 512) * 2048 + k];
    else if (row < 525) v = camw[(row - 522) * 2048 + k];
    Wp[gid] = f2bf(v);
}

// ---- pack root/pose weights to bf16 [o2][kk], kk = j*512+o (coords excluded) ----
__global__ void pack_w2_kernel(const float* __restrict__ root_w,
                               const float* __restrict__ pose_w,
                               unsigned short* __restrict__ W2p) {
    int gid = blockIdx.x * 256 + threadIdx.x;
    if (gid >= W2P_ELEMS) return;
    int o2 = gid / 15360;
    int kk = gid - o2 * 15360;
    int j  = kk >> 9;
    int o  = kk & 511;
    int col = j * 515 + o;
    float v = 0.f;
    if (o2 < 6)        v = root_w[o2 * 15450 + col];
    else if (o2 < 132) v = pose_w[(o2 - 6) * 15450 + col];
    W2p[gid] = f2bf(v);
}

// ---- fold BN(eval)+conv bias into per-channel scale/bias ----
__global__ void bn_prep_kernel(const float* cb, const float* g, const float* be,
                               const float* m, const float* v, float* sbws) {
    int o = blockIdx.x * 256 + threadIdx.x;
    if (o >= 512) return;
    float s = g[o] * rsqrtf(v[o] + 1e-5f);
    sbws[2 * o]     = s;
    sbws[2 * o + 1] = be[o] + s * (cb[o] - m[o]);
}

// ---- init output: root/pose = bias + joint-coord columns; shape/cam = bias ----
__global__ void init_out_kernel(const float* __restrict__ jc,
                                const float* __restrict__ root_w,
                                const float* __restrict__ pose_w,
                                const float* __restrict__ root_b,
                                const float* __restrict__ pose_b,
                                const float* __restrict__ shape_b,
                                const float* __restrict__ cam_b,
                                float* __restrict__ out) {
    int gid = blockIdx.x * 256 + threadIdx.x;  // exactly 74240 threads
    if (gid < 67584) {
        int b  = gid / 132;
        int o2 = gid - b * 132;
        const float* wr;
        float acc;
        if (o2 < 6) { wr = root_w + o2 * 15450;       acc = root_b[o2]; }
        else        { wr = pose_w + (o2 - 6) * 15450; acc = pose_b[o2 - 6]; }
        const float* jb = jc + b * 90;
        #pragma unroll
        for (int j = 0; j < 30; ++j) {
            acc += jb[j * 3 + 0] * wr[j * 515 + 512];
            acc += jb[j * 3 + 1] * wr[j * 515 + 513];
            acc += jb[j * 3 + 2] * wr[j * 515 + 514];
        }
        if (o2 < 6) out[b * 6 + o2] = acc;
        else        out[3072 + b * 126 + (o2 - 6)] = acc;
    } else {
        int e = gid - 67584;   // < 6656 = 512*13
        int b = e / 13;
        int s = e - b * 13;
        if (s < 10) out[67584 + b * 10 + s] = shape_b[s];
        else        out[72704 + b * 3 + (s - 10)] = cam_b[s - 10];
    }
}

// ---- main fused kernel: per-batch conv GEMM (+pooled rows) + BN/ReLU + bilinear sample ----
__global__ __launch_bounds__(256, 2)
void conv_main_kernel(const float* __restrict__ img,
                      const float* __restrict__ jc,
                      const unsigned short* __restrict__ Wp,
                      const float* __restrict__ sbws,
                      unsigned short* __restrict__ sampled,
                      float* __restrict__ out) {
    __shared__ __align__(16) char smem[65536];
    const int t    = threadIdx.x;
    const int lane = t & 63;
    const int w    = t >> 6;
    const int l15  = lane & 15;
    const int quad = lane >> 4;
    const int b    = blockIdx.x;

    f32x4 acc[8][4];
    f32x4 accX;
    #pragma unroll
    for (int mi = 0; mi < 8; ++mi)
        #pragma unroll
        for (int nt = 0; nt < 4; ++nt)
            acc[mi][nt] = (f32x4){0.f, 0.f, 0.f, 0.f};
    accX = (f32x4){0.f, 0.f, 0.f, 0.f};

    // B staging: lane owns hw position = lane, k-chunk = w*8..w*8+7 (one b128 write)
    const float* gBbase = img + (size_t)b * 131072 + (size_t)(w * 8) * 64 + lane;

    for (int kt = 0; kt < 64; ++kt) {
        __syncthreads();
        // A: 528x32 bf16 pre-packed tile, contiguous, 2112 16B chunks
        const int4* gA = (const int4*)(Wp + (size_t)kt * 16896);
        int4 ta[8];
        #pragma unroll
        for (int i = 0; i < 8; ++i) ta[i] = gA[t + 256 * i];
        int4 ta8;
        if (t < 64) ta8 = gA[t + 2048];
        // B: 32x64 f32 tile, coalesced dword loads
        const float* gB = gBbase + (size_t)(kt * 32) * 64;
        float fb[8];
        #pragma unroll
        for (int j = 0; j < 8; ++j) fb[j] = gB[j * 64];

        #pragma unroll
        for (int i = 0; i < 8; ++i) {
            int c2 = t + 256 * i;
            *(int4*)(smem + (c2 >> 2) * 80 + (c2 & 3) * 16) = ta[i];
        }
        if (t < 64) {
            int c2 = t + 2048;
            *(int4*)(smem + (c2 >> 2) * 80 + (c2 & 3) * 16) = ta8;
        }
        {
            int4 bv;
            bv.x = (int)((uint32_t)f2bf(fb[0]) | ((uint32_t)f2bf(fb[1]) << 16));
            bv.y = (int)((uint32_t)f2bf(fb[2]) | ((uint32_t)f2bf(fb[3]) << 16));
            bv.z = (int)((uint32_t)f2bf(fb[4]) | ((uint32_t)f2bf(fb[5]) << 16));
            bv.w = (int)((uint32_t)f2bf(fb[6]) | ((uint32_t)f2bf(fb[7]) << 16));
            *(int4*)(smem + B_OFF + lane * 80 + w * 16) = bv;
        }
        __syncthreads();

        bf16x8 bfr0 = *(const bf16x8*)(smem + B_OFF + (0  + l15) * 80 + quad * 16);
        bf16x8 bfr1 = *(const bf16x8*)(smem + B_OFF + (16 + l15) * 80 + quad * 16);
        bf16x8 bfr2 = *(const bf16x8*)(smem + B_OFF + (32 + l15) * 80 + quad * 16);
        bf16x8 bfr3 = *(const bf16x8*)(smem + B_OFF + (48 + l15) * 80 + quad * 16);
        #pragma unroll
        for (int mi = 0; mi < 8; ++mi) {
            bf16x8 afr = *(const bf16x8*)(smem + (w * 128 + mi * 16 + l15) * 80 + quad * 16);
            acc[mi][0] = __builtin_amdgcn_mfma_f32_16x16x32_bf16(afr, bfr0, acc[mi][0], 0, 0, 0);
            acc[mi][1] = __builtin_amdgcn_mfma_f32_16x16x32_bf16(afr, bfr1, acc[mi][1], 0, 0, 0);
            acc[mi][2] = __builtin_amdgcn_mfma_f32_16x16x32_bf16(afr, bfr2, acc[mi][2], 0, 0, 0);
            acc[mi][3] = __builtin_amdgcn_mfma_f32_16x16x32_bf16(afr, bfr3, acc[mi][3], 0, 0, 0);
        }
        {   // pooled rows 512..527 (shape_w/cam_w appended); wave w covers n-tile w
            bf16x8 afrX = *(const bf16x8*)(smem + (512 + l15) * 80 + quad * 16);
            bf16x8 bfrW = *(const bf16x8*)(smem + B_OFF + (w * 16 + l15) * 80 + quad * 16);
            accX = __builtin_amdgcn_mfma_f32_16x16x32_bf16(afrX, bfrW, accX, 0, 0, 0);
        }
    }

    __syncthreads();   // staging LDS dead; reuse as f (512 rows x 64 pos bf16, XOR swizzle)
    const float2* sb2 = (const float2*)sbws;
    #pragma unroll
    for (int mi = 0; mi < 8; ++mi) {
        #pragma unroll
        for (int r = 0; r < 4; ++r) {
            int row = w * 128 + mi * 16 + quad * 4 + r;
            float2 sb = sb2[row];
            #pragma unroll
            for (int nt = 0; nt < 4; ++nt) {
                int col = nt * 16 + l15;
                float v = fmaxf(acc[mi][nt][r] * sb.x + sb.y, 0.f);
                *(unsigned short*)(smem + row * 128 + (((col + row) & 63) << 1)) = f2bf(v);
            }
        }
    }
    // shape/cam: mean over 64 hw of pooled rows, atomically added onto bias
    #pragma unroll
    for (int r = 0; r < 4; ++r) {
        float v = accX[r];
        v += __shfl_xor(v, 1);
        v += __shfl_xor(v, 2);
        v += __shfl_xor(v, 4);
        v += __shfl_xor(v, 8);
        if (l15 == 0) {
            int s = quad * 4 + r;
            float val = v * 0.015625f;
            if (s < 10)      atomicAdd(out + 67584 + b * 10 + s, val);
            else if (s < 13) atomicAdd(out + 72704 + b * 3 + (s - 10), val);
        }
    }
    __syncthreads();

    // bilinear sampling: thread handles channels o=2t,2t+1; joint j == s for all threads
    const float* jcb = jc + b * 90;
    unsigned int* outsamp = (unsigned int*)(sampled + (size_t)b * 15360);
    const int o = 2 * t;
    for (int s = 0; s < 30; ++s) {
        float x = jcb[s * 3 + 0];
        float y = jcb[s * 3 + 1];
        float x0f = floorf(x), y0f = floorf(y);
        int x0 = (int)x0f, y0 = (int)y0f;
        int x1 = x0 + 1, y1 = y0 + 1;
        float wx1 = x - x0f, wy1 = y - y0f;
        float wx0 = 1.f - wx1, wy0 = 1.f - wy1;
        float vx0 = (x0 >= 0 && x0 < 8) ? 1.f : 0.f;
        float vx1 = (x1 >= 0 && x1 < 8) ? 1.f : 0.f;
        float vy0 = (y0 >= 0 && y0 < 8) ? 1.f : 0.f;
        float vy1 = (y1 >= 0 && y1 < 8) ? 1.f : 0.f;
        int cx0 = min(max(x0, 0), 7), cx1 = min(max(x1, 0), 7);
        int cy0 = min(max(y0, 0), 7), cy1 = min(max(y1, 0), 7);
        int p00 = cy0 * 8 + cx0, p01 = cy0 * 8 + cx1;
        int p10 = cy1 * 8 + cx0, p11 = cy1 * 8 + cx1;
        float w00 = wy0 * wx0 * vy0 * vx0, w01 = wy0 * wx1 * vy0 * vx1;
        float w10 = wy1 * wx0 * vy1 * vx0, w11 = wy1 * wx1 * vy1 * vx1;
        float vA = w00 * bf2f(*(unsigned short*)(smem + o * 128 + (((p00 + o) & 63) << 1)))
                 + w01 * bf2f(*(unsigned short*)(smem + o * 128 + (((p01 + o) & 63) << 1)))
                 + w10 * bf2f(*(unsigned short*)(smem + o * 128 + (((p10 + o) & 63) << 1)))
                 + w11 * bf2f(*(unsigned short*)(smem + o * 128 + (((p11 + o) & 63) << 1)));
        int o1 = o + 1;
        float vB = w00 * bf2f(*(unsigned short*)(smem + o1 * 128 + (((p00 + o1) & 63) << 1)))
                 + w01 * bf2f(*(unsigned short*)(smem + o1 * 128 + (((p01 + o1) & 63) << 1)))
                 + w10 * bf2f(*(unsigned short*)(smem + o1 * 128 + (((p10 + o1) & 63) << 1)))
                 + w11 * bf2f(*(unsigned short*)(smem + o1 * 128 + (((p11 + o1) & 63) << 1)));
        outsamp[s * 256 + t] = (uint32_t)f2bf(vA) | ((uint32_t)f2bf(vB) << 16);
    }
}

// ---- head GEMM: out(512x132) += feat(512x15360)bf16 @ W2p^T, K split by joint ----
__global__ __launch_bounds__(256, 4)
void gemm2_kernel(const unsigned short* __restrict__ sampled,
                  const unsigned short* __restrict__ W2p,
                  float* __restrict__ out) {
    __shared__ __align__(16) char smem[16640];   // A: 64*80=5120, B: 144*80=11520
    const int t    = threadIdx.x;
    const int lane = t & 63;
    const int w    = t >> 6;
    const int l15  = lane & 15;
    const int quad = lane >> 4;
    const int m0   = blockIdx.x * 64;
    const int j    = blockIdx.y;

    f32x4 acc[9];
    #pragma unroll
    for (int nt = 0; nt < 9; ++nt) acc[nt] = (f32x4){0.f, 0.f, 0.f, 0.f};

    for (int kt = 0; kt < 16; ++kt) {
        __syncthreads();
        {
            int r = t >> 2, ci = t & 3;
            int4 d = *(const int4*)(sampled + (size_t)(m0 + r) * 15360 + j * 512 + kt * 32 + ci * 8);
            *(int4*)(smem + r * 80 + ci * 16) = d;
        }
        #pragma unroll
        for (int i = 0; i < 3; ++i) {
            int c2 = t + 256 * i;
            if (c2 < 576) {
                int r = c2 >> 2, ci = c2 & 3;
                int4 d = *(const int4*)(W2p + (size_t)r * 15360 + j * 512 + kt * 32 + ci * 8);
                *(int4*)(smem + 5120 + r * 80 + ci * 16) = d;
            }
        }
        __syncthreads();
        bf16x8 a = *(const bf16x8*)(smem + (w * 16 + l15) * 80 + quad * 16);
        #pragma unroll
        for (int nt = 0; nt < 9; ++nt) {
            bf16x8 bfv = *(const bf16x8*)(smem + 5120 + (nt * 16 + l15) * 80 + quad * 16);
            acc[nt] = __builtin_amdgcn_mfma_f32_16x16x32_bf16(a, bfv, acc[nt], 0, 0, 0);
        }
    }
    #pragma unroll
    for (int nt = 0; nt < 9; ++nt) {
        int o2 = nt * 16 + l15;
        if (o2 < 132) {
            #pragma unroll
            for (int r = 0; r < 4; ++r) {
                int m = m0 + w * 16 + quad * 4 + r;
                float v = acc[nt][r];
                if (o2 < 6) atomicAdd(out + m * 6 + o2, v);
                else        atomicAdd(out + 3072 + m * 126 + (o2 - 6), v);
            }
        }
    }
}

extern "C" void kernel_launch(void* const* d_in, const int* in_sizes, int n_in,
                              void* d_out, int out_size, void* d_ws, size_t ws_size,
                              hipStream_t stream) {
    const float* img     = (const float*)d_in[0];
    const float* jc      = (const float*)d_in[1];
    const float* conv_w  = (const float*)d_in[2];
    const float* conv_b  = (const float*)d_in[3];
    const float* bn_g    = (const float*)d_in[4];
    const float* bn_be   = (const float*)d_in[5];
    const float* bn_m    = (const float*)d_in[6];
    const float* bn_v    = (const float*)d_in[7];
    const float* root_w  = (const float*)d_in[8];
    const float* root_b  = (const float*)d_in[9];
    const float* pose_w  = (const float*)d_in[10];
    const float* pose_b  = (const float*)d_in[11];
    const float* shape_w = (const float*)d_in[12];
    const float* shape_b = (const float*)d_in[13];
    const float* cam_w   = (const float*)d_in[14];
    const float* cam_b   = (const float*)d_in[15];
    float* out = (float*)d_out;
    char* ws = (char*)d_ws;

    unsigned short* Wp   = (unsigned short*)(ws);                               // 2,162,688 B
    unsigned short* W2p  = (unsigned short*)(ws + 2162688);                     // 4,423,680 B
    unsigned short* samp = (unsigned short*)(ws + 2162688 + 4423680);           // 15,728,640 B
    float* sbws          = (float*)(ws + 2162688 + 4423680 + 15728640);         // 4,096 B

    pack_convw_kernel<<<4224, 256, 0, stream>>>(conv_w, shape_w, cam_w, Wp);
    pack_w2_kernel<<<8640, 256, 0, stream>>>(root_w, pose_w, W2p);
    bn_prep_kernel<<<2, 256, 0, stream>>>(conv_b, bn_g, bn_be, bn_m, bn_v, sbws);
    init_out_kernel<<<290, 256, 0, stream>>>(jc, root_w, pose_w, root_b, pose_b,
                                             shape_b, cam_b, out);
    conv_main_kernel<<<512, 256, 0, stream>>>(img, jc, Wp, sbws, samp, out);
    gemm2_kernel<<<dim3(8, 30), 256, 0, stream>>>(samp, W2p, out);
}

// Round 2
// 473.466 us; speedup vs baseline: 1.0307x; 1.0307x over previous
//
#include <hip/hip_runtime.h>
#include <stdint.h>

typedef __attribute__((ext_vector_type(8))) short bf16x8;
typedef __attribute__((ext_vector_type(4))) float f32x4;

__device__ __forceinline__ unsigned short f2bf(float f) {
    union { float f; uint32_t u; } v; v.f = f;
    uint32_t r = (v.u + 0x7FFFu + ((v.u >> 16) & 1u)) >> 16;
    return (unsigned short)r;
}
__device__ __forceinline__ float bf2f(unsigned short u) {
    union { uint32_t u; float f; } v; v.u = ((uint32_t)u) << 16; return v.f;
}

#define WP_ELEMS  1081344      // 64 ktiles * 528 rows * 32 k
#define K2        15456        // head-GEMM K: 30*512 sampled + 96 coord slots (90 used)
#define W2P_ELEMS (144 * K2)   // 2,225,664
#define B_OFF     42240        // LDS byte offset of B staging (A is 528*80=42240)

// ---- pack conv weights (+shape/cam rows 512..524) to bf16, K-tiled [kt][row][k] ----
__global__ void pack_convw_kernel(const float* __restrict__ cw,
                                  const float* __restrict__ sw,
                                  const float* __restrict__ camw,
                                  unsigned short* __restrict__ Wp) {
    int gid = blockIdx.x * 256 + threadIdx.x;
    if (gid >= WP_ELEMS) return;
    int kt  = gid / 16896;
    int rem = gid - kt * 16896;
    int row = rem >> 5;
    int c   = rem & 31;
    int k   = kt * 32 + c;
    float v = 0.f;
    if (row < 512)      v = cw[row * 2048 + k];
    else if (row < 522) v = sw[(row - 512) * 2048 + k];
    else if (row < 525) v = camw[(row - 522) * 2048 + k];
    Wp[gid] = f2bf(v);
}

// ---- pack root/pose weights to bf16 [o2][K2]; cols 15360.. are the coord columns ----
__global__ void pack_w2_kernel(const float* __restrict__ root_w,
                               const float* __restrict__ pose_w,
                               unsigned short* __restrict__ W2p) {
    int gid = blockIdx.x * 256 + threadIdx.x;
    if (gid >= W2P_ELEMS) return;
    int o2 = gid / K2;
    int kk = gid - o2 * K2;
    float v = 0.f;
    if (o2 < 132) {
        const float* wr = (o2 < 6) ? (root_w + o2 * 15450) : (pose_w + (o2 - 6) * 15450);
        if (kk < 15360) {
            int j = kk >> 9;
            int o = kk & 511;
            v = wr[j * 515 + o];
        } else {
            int c = kk - 15360;
            if (c < 90) {
                int j = c / 3, d = c - 3 * j;
                v = wr[j * 515 + 512 + d];
            }
        }
    }
    W2p[gid] = f2bf(v);
}

// ---- fold BN(eval)+conv bias into per-channel scale/bias ----
__global__ void bn_prep_kernel(const float* cb, const float* g, const float* be,
                               const float* m, const float* v, float* sbws) {
    int o = blockIdx.x * 256 + threadIdx.x;
    if (o >= 512) return;
    float s = g[o] * rsqrtf(v[o] + 1e-5f);
    sbws[2 * o]     = s;
    sbws[2 * o + 1] = be[o] + s * (cb[o] - m[o]);
}

// ---- main fused kernel: per-batch conv GEMM (+pooled rows) + BN/ReLU + bilinear sample ----
__global__ __launch_bounds__(256, 2)
void conv_main_kernel(const float* __restrict__ img,
                      const float* __restrict__ jc,
                      const unsigned short* __restrict__ Wp,
                      const float* __restrict__ sbws,
                      const float* __restrict__ shape_b,
                      const float* __restrict__ cam_b,
                      unsigned short* __restrict__ sampled,
                      float* __restrict__ out) {
    __shared__ __align__(16) char smem[65536 + 256];
    const int t    = threadIdx.x;
    const int lane = t & 63;
    const int w    = t >> 6;
    const int l15  = lane & 15;
    const int quad = lane >> 4;
    const int b    = blockIdx.x;

    f32x4 acc[8][4];
    f32x4 accX;
    #pragma unroll
    for (int mi = 0; mi < 8; ++mi)
        #pragma unroll
        for (int nt = 0; nt < 4; ++nt)
            acc[mi][nt] = (f32x4){0.f, 0.f, 0.f, 0.f};
    accX = (f32x4){0.f, 0.f, 0.f, 0.f};

    // B staging: lane owns hw position = lane, k-chunk = w*8..w*8+7 (one b128 write)
    const float* gBbase = img + (size_t)b * 131072 + (size_t)(w * 8) * 64 + lane;

    for (int kt = 0; kt < 64; ++kt) {
        __syncthreads();
        // A: 528x32 bf16 pre-packed tile, contiguous, 2112 16B chunks
        const int4* gA = (const int4*)(Wp + (size_t)kt * 16896);
        int4 ta[8];
        #pragma unroll
        for (int i = 0; i < 8; ++i) ta[i] = gA[t + 256 * i];
        int4 ta8;
        if (t < 64) ta8 = gA[t + 2048];
        // B: 32x64 f32 tile, coalesced dword loads
        const float* gB = gBbase + (size_t)(kt * 32) * 64;
        float fb[8];
        #pragma unroll
        for (int j = 0; j < 8; ++j) fb[j] = gB[j * 64];

        #pragma unroll
        for (int i = 0; i < 8; ++i) {
            int c2 = t + 256 * i;
            *(int4*)(smem + (c2 >> 2) * 80 + (c2 & 3) * 16) = ta[i];
        }
        if (t < 64) {
            int c2 = t + 2048;
            *(int4*)(smem + (c2 >> 2) * 80 + (c2 & 3) * 16) = ta8;
        }
        {
            int4 bv;
            bv.x = (int)((uint32_t)f2bf(fb[0]) | ((uint32_t)f2bf(fb[1]) << 16));
            bv.y = (int)((uint32_t)f2bf(fb[2]) | ((uint32_t)f2bf(fb[3]) << 16));
            bv.z = (int)((uint32_t)f2bf(fb[4]) | ((uint32_t)f2bf(fb[5]) << 16));
            bv.w = (int)((uint32_t)f2bf(fb[6]) | ((uint32_t)f2bf(fb[7]) << 16));
            *(int4*)(smem + B_OFF + lane * 80 + w * 16) = bv;
        }
        __syncthreads();

        bf16x8 bfr0 = *(const bf16x8*)(smem + B_OFF + (0  + l15) * 80 + quad * 16);
        bf16x8 bfr1 = *(const bf16x8*)(smem + B_OFF + (16 + l15) * 80 + quad * 16);
        bf16x8 bfr2 = *(const bf16x8*)(smem + B_OFF + (32 + l15) * 80 + quad * 16);
        bf16x8 bfr3 = *(const bf16x8*)(smem + B_OFF + (48 + l15) * 80 + quad * 16);
        #pragma unroll
        for (int mi = 0; mi < 8; ++mi) {
            bf16x8 afr = *(const bf16x8*)(smem + (w * 128 + mi * 16 + l15) * 80 + quad * 16);
            acc[mi][0] = __builtin_amdgcn_mfma_f32_16x16x32_bf16(afr, bfr0, acc[mi][0], 0, 0, 0);
            acc[mi][1] = __builtin_amdgcn_mfma_f32_16x16x32_bf16(afr, bfr1, acc[mi][1], 0, 0, 0);
            acc[mi][2] = __builtin_amdgcn_mfma_f32_16x16x32_bf16(afr, bfr2, acc[mi][2], 0, 0, 0);
            acc[mi][3] = __builtin_amdgcn_mfma_f32_16x16x32_bf16(afr, bfr3, acc[mi][3], 0, 0, 0);
        }
        {   // pooled rows 512..527 (shape_w/cam_w appended); wave w covers n-tile w
            bf16x8 afrX = *(const bf16x8*)(smem + (512 + l15) * 80 + quad * 16);
            bf16x8 bfrW = *(const bf16x8*)(smem + B_OFF + (w * 16 + l15) * 80 + quad * 16);
            accX = __builtin_amdgcn_mfma_f32_16x16x32_bf16(afrX, bfrW, accX, 0, 0, 0);
        }
    }

    __syncthreads();   // staging LDS dead; reuse as f (512 rows x 64 pos bf16, XOR swizzle)
    const float2* sb2 = (const float2*)sbws;
    #pragma unroll
    for (int mi = 0; mi < 8; ++mi) {
        #pragma unroll
        for (int r = 0; r < 4; ++r) {
            int row = w * 128 + mi * 16 + quad * 4 + r;
            float2 sb = sb2[row];
            #pragma unroll
            for (int nt = 0; nt < 4; ++nt) {
                int col = nt * 16 + l15;
                float v = fmaxf(acc[mi][nt][r] * sb.x + sb.y, 0.f);
                *(unsigned short*)(smem + row * 128 + (((col + row) & 63) << 1)) = f2bf(v);
            }
        }
    }
    // shape/cam: per-wave shuffle reduce (16 positions), cross-wave via LDS red area
    float* red = (float*)(smem + 65536);
    #pragma unroll
    for (int r = 0; r < 4; ++r) {
        float v = accX[r];
        v += __shfl_xor(v, 1);
        v += __shfl_xor(v, 2);
        v += __shfl_xor(v, 4);
        v += __shfl_xor(v, 8);
        if (l15 == 0) red[w * 16 + quad * 4 + r] = v;
    }
    __syncthreads();

    if (t < 16) {
        float v = (red[t] + red[16 + t] + red[32 + t] + red[48 + t]) * 0.015625f;
        if (t < 10)      out[67584 + b * 10 + t] = v + shape_b[t];
        else if (t < 13) out[72704 + b * 3 + (t - 10)] = v + cam_b[t - 10];
    }
    // append joint coords (bf16) as K-columns 15360..15455 of samp (pad 90..95 = 0)
    const float* jcb = jc + b * 90;
    if (t < 96) {
        float v = (t < 90) ? jcb[t] : 0.f;
        sampled[(size_t)b * K2 + 15360 + t] = f2bf(v);
    }

    // bilinear sampling: thread handles channels o=2t,2t+1; joint j == s for all threads
    unsigned int* outsamp = (unsigned int*)(sampled + (size_t)b * K2);
    const int o = 2 * t;
    for (int s = 0; s < 30; ++s) {
        float x = jcb[s * 3 + 0];
        float y = jcb[s * 3 + 1];
        float x0f = floorf(x), y0f = floorf(y);
        int x0 = (int)x0f, y0 = (int)y0f;
        int x1 = x0 + 1, y1 = y0 + 1;
        float wx1 = x - x0f, wy1 = y - y0f;
        float wx0 = 1.f - wx1, wy0 = 1.f - wy1;
        float vx0 = (x0 >= 0 && x0 < 8) ? 1.f : 0.f;
        float vx1 = (x1 >= 0 && x1 < 8) ? 1.f : 0.f;
        float vy0 = (y0 >= 0 && y0 < 8) ? 1.f : 0.f;
        float vy1 = (y1 >= 0 && y1 < 8) ? 1.f : 0.f;
        int cx0 = min(max(x0, 0), 7), cx1 = min(max(x1, 0), 7);
        int cy0 = min(max(y0, 0), 7), cy1 = min(max(y1, 0), 7);
        int p00 = cy0 * 8 + cx0, p01 = cy0 * 8 + cx1;
        int p10 = cy1 * 8 + cx0, p11 = cy1 * 8 + cx1;
        float w00 = wy0 * wx0 * vy0 * vx0, w01 = wy0 * wx1 * vy0 * vx1;
        float w10 = wy1 * wx0 * vy1 * vx0, w11 = wy1 * wx1 * vy1 * vx1;
        float vA = w00 * bf2f(*(unsigned short*)(smem + o * 128 + (((p00 + o) & 63) << 1)))
                 + w01 * bf2f(*(unsigned short*)(smem + o * 128 + (((p01 + o) & 63) << 1)))
                 + w10 * bf2f(*(unsigned short*)(smem + o * 128 + (((p10 + o) & 63) << 1)))
                 + w11 * bf2f(*(unsigned short*)(smem + o * 128 + (((p11 + o) & 63) << 1)));
        int o1 = o + 1;
        float vB = w00 * bf2f(*(unsigned short*)(smem + o1 * 128 + (((p00 + o1) & 63) << 1)))
                 + w01 * bf2f(*(unsigned short*)(smem + o1 * 128 + (((p01 + o1) & 63) << 1)))
                 + w10 * bf2f(*(unsigned short*)(smem + o1 * 128 + (((p10 + o1) & 63) << 1)))
                 + w11 * bf2f(*(unsigned short*)(smem + o1 * 128 + (((p11 + o1) & 63) << 1)));
        outsamp[s * 256 + t] = (uint32_t)f2bf(vA) | ((uint32_t)f2bf(vB) << 16);
    }
}

// ---- head GEMM: partials(31x8 blocks of 64x144) = feat(512xK2)bf16 @ W2p^T, K split by joint ----
__global__ __launch_bounds__(256, 4)
void gemm2_kernel(const unsigned short* __restrict__ sampled,
                  const unsigned short* __restrict__ W2p,
                  float* __restrict__ part) {
    __shared__ __align__(16) char smem[16640];   // A: 64*80=5120, B: 144*80=11520
    const int t    = threadIdx.x;
    const int lane = t & 63;
    const int w    = t >> 6;
    const int l15  = lane & 15;
    const int quad = lane >> 4;
    const int m0   = blockIdx.x * 64;
    const int j    = blockIdx.y;
    const int k0   = j * 512;              // j==30 -> 15360 (coord columns)
    const int ktn  = (j == 30) ? 3 : 16;

    f32x4 acc[9];
    #pragma unroll
    for (int nt = 0; nt < 9; ++nt) acc[nt] = (f32x4){0.f, 0.f, 0.f, 0.f};

    for (int kt = 0; kt < ktn; ++kt) {
        __syncthreads();
        {
            int r = t >> 2, ci = t & 3;
            int4 d = *(const int4*)(sampled + (size_t)(m0 + r) * K2 + k0 + kt * 32 + ci * 8);
            *(int4*)(smem + r * 80 + ci * 16) = d;
        }
        #pragma unroll
        for (int i = 0; i < 3; ++i) {
            int c2 = t + 256 * i;
            if (c2 < 576) {
                int r = c2 >> 2, ci = c2 & 3;
                int4 d = *(const int4*)(W2p + (size_t)r * K2 + k0 + kt * 32 + ci * 8);
                *(int4*)(smem + 5120 + r * 80 + ci * 16) = d;
            }
        }
        __syncthreads();
        bf16x8 a = *(const bf16x8*)(smem + (w * 16 + l15) * 80 + quad * 16);
        #pragma unroll
        for (int nt = 0; nt < 9; ++nt) {
            bf16x8 bfv = *(const bf16x8*)(smem + 5120 + (nt * 16 + l15) * 80 + quad * 16);
            acc[nt] = __builtin_amdgcn_mfma_f32_16x16x32_bf16(a, bfv, acc[nt], 0, 0, 0);
        }
    }
    float* pout = part + (size_t)(j * 8 + blockIdx.x) * 9216;   // 64*144
    #pragma unroll
    for (int nt = 0; nt < 9; ++nt) {
        #pragma unroll
        for (int r = 0; r < 4; ++r) {
            pout[(w * 16 + quad * 4 + r) * 144 + nt * 16 + l15] = acc[nt][r];
        }
    }
}

// ---- sum 31 K-partials + bias -> final root/pose outputs ----
__global__ void reduce_out_kernel(const float* __restrict__ part,
                                  const float* __restrict__ root_b,
                                  const float* __restrict__ pose_b,
                                  float* __restrict__ out) {
    int gid = blockIdx.x * 256 + threadIdx.x;    // exactly 67584
    int m  = gid / 132;
    int o2 = gid - m * 132;
    float s = (o2 < 6) ? root_b[o2] : pose_b[o2 - 6];
    const float* p = part + (size_t)(m >> 6) * 9216 + (m & 63) * 144 + o2;
    #pragma unroll
    for (int j = 0; j < 31; ++j) s += p[(size_t)j * 8 * 9216];
    if (o2 < 6) out[m * 6 + o2] = s;
    else        out[3072 + m * 126 + (o2 - 6)] = s;
}

extern "C" void kernel_launch(void* const* d_in, const int* in_sizes, int n_in,
                              void* d_out, int out_size, void* d_ws, size_t ws_size,
                              hipStream_t stream) {
    const float* img     = (const float*)d_in[0];
    const float* jc      = (const float*)d_in[1];
    const float* conv_w  = (const float*)d_in[2];
    const float* conv_b  = (const float*)d_in[3];
    const float* bn_g    = (const float*)d_in[4];
    const float* bn_be   = (const float*)d_in[5];
    const float* bn_m    = (const float*)d_in[6];
    const float* bn_v    = (const float*)d_in[7];
    const float* root_w  = (const float*)d_in[8];
    const float* root_b  = (const float*)d_in[9];
    const float* pose_w  = (const float*)d_in[10];
    const float* pose_b  = (const float*)d_in[11];
    const float* shape_w = (const float*)d_in[12];
    const float* shape_b = (const float*)d_in[13];
    const float* cam_w   = (const float*)d_in[14];
    const float* cam_b   = (const float*)d_in[15];
    float* out = (float*)d_out;
    char* ws = (char*)d_ws;

    unsigned short* Wp   = (unsigned short*)(ws);                    // 2,162,688 B
    unsigned short* W2p  = (unsigned short*)(ws + 2162688);          // 4,451,328 B
    unsigned short* samp = (unsigned short*)(ws + 6614016);          // 15,826,944 B
    float* part          = (float*)(ws + 22440960);                  // 9,142,272 B
    float* sbws          = (float*)(ws + 31583232);                  // 4,096 B

    pack_convw_kernel<<<4224, 256, 0, stream>>>(conv_w, shape_w, cam_w, Wp);
    pack_w2_kernel<<<8694, 256, 0, stream>>>(root_w, pose_w, W2p);
    bn_prep_kernel<<<2, 256, 0, stream>>>(conv_b, bn_g, bn_be, bn_m, bn_v, sbws);
    conv_main_kernel<<<512, 256, 0, stream>>>(img, jc, Wp, sbws, shape_b, cam_b,
                                              samp, out);
    gemm2_kernel<<<dim3(8, 31), 256, 0, stream>>>(samp, W2p, part);
    reduce_out_kernel<<<264, 256, 0, stream>>>(part, root_b, pose_b, out);
}